// Round 2
// baseline (366.447 us; speedup 1.0000x reference)
//
#include <hip/hip_runtime.h>
#include <hip/hip_bf16.h>

#define SEQ   2048
#define DIMC  1024
#define NH    16
#define HD    64
#define QKV3  3072
#define NB    2

typedef __attribute__((ext_vector_type(8))) short bf16x8;
typedef __attribute__((ext_vector_type(4))) float f32x4;

__device__ __forceinline__ unsigned short f2bf(float f){
  union { float f; unsigned int u; } v; v.f = f;
  return (unsigned short)((v.u + 0x7fffu + ((v.u >> 16) & 1u)) >> 16);
}
__device__ __forceinline__ float bf2f(unsigned short h){
  union { unsigned int u; float f; } v; v.u = ((unsigned int)h) << 16; return v.f;
}

__device__ __forceinline__ void async_lds16(void* lds, const void* g){
  __builtin_amdgcn_global_load_lds(
      (const __attribute__((address_space(1))) void*)g,
      (__attribute__((address_space(3))) void*)lds, 16, 0, 0);
}

// ---------------- f32 -> bf16 convert ----------------
__global__ __launch_bounds__(256) void k_cvt(const float* __restrict__ in,
                                             unsigned short* __restrict__ out, int n4){
  int i = blockIdx.x * 256 + threadIdx.x;
  if (i >= n4) return;
  const float4 v = ((const float4*)in)[i];
  union { unsigned short s[4]; unsigned long long u; } p;
  p.s[0] = f2bf(v.x); p.s[1] = f2bf(v.y); p.s[2] = f2bf(v.z); p.s[3] = f2bf(v.w);
  *(unsigned long long*)(out + (size_t)i * 4) = p.u;
}

// ---------------- RoPE cos/sin table: tab[n*32+j] = {cos,sin}(n * invfreq_j) ----------------
__global__ __launch_bounds__(256) void k_tab(float2* __restrict__ tab){
  int idx = blockIdx.x * 256 + threadIdx.x;          // 2048*32 = 65536
  int n = idx >> 5, j = idx & 31;
  float inv = 1.0f / powf(10000.0f, (float)(2 * j) * (1.0f / 64.0f));
  float f = (float)n * inv;
  tab[idx] = make_float2(cosf(f), sinf(f));
}

// ---------------- GEMM: C[M,N] = A[M,K] * B[N,K]^T (bf16 in, f32 acc) ----------------
// 128x128 tile, BK=64, 4 waves (2x2), 16x16x32 MFMA  (m97 structure)
template<int OUT_BF16>
__global__ __launch_bounds__(256) void k_gemm(const unsigned short* __restrict__ A,
                                              const unsigned short* __restrict__ Bm,
                                              void* __restrict__ Cp, int M, int N, int K){
  __shared__ unsigned short As[128 * 64];
  __shared__ unsigned short Bs[128 * 64];
  const int tid = threadIdx.x, wave = tid >> 6, lane = tid & 63;
  const int nbn = N >> 7;
  const int bm = blockIdx.x / nbn, bn = blockIdx.x % nbn;
  const int m0 = bm << 7, n0 = bn << 7;
  const int wr = wave >> 1, wc = wave & 1;

  f32x4 acc[4][4];
#pragma unroll
  for (int i = 0; i < 4; i++)
#pragma unroll
    for (int j = 0; j < 4; j++) acc[i][j] = (f32x4){0.f, 0.f, 0.f, 0.f};

  for (int k0 = 0; k0 < K; k0 += 64){
#pragma unroll
    for (int c = 0; c < 4; c++){
      const int e = c * 2048 + tid * 8;             // elem index in 128x64 tile (row-major)
      const int row = e >> 6, col = e & 63;
      async_lds16(As + c * 2048 + wave * 512, A + (size_t)(m0 + row) * K + k0 + col);
      async_lds16(Bs + c * 2048 + wave * 512, Bm + (size_t)(n0 + row) * K + k0 + col);
    }
    __syncthreads();
#pragma unroll
    for (int ks = 0; ks < 2; ks++){
      const int kk = ks * 32 + (lane >> 4) * 8;
      bf16x8 af[4], bfr[4];
#pragma unroll
      for (int i = 0; i < 4; i++){
        af[i]  = *(const bf16x8*)&As[(wr * 64 + i * 16 + (lane & 15)) * 64 + kk];
        bfr[i] = *(const bf16x8*)&Bs[(wc * 64 + i * 16 + (lane & 15)) * 64 + kk];
      }
#pragma unroll
      for (int i = 0; i < 4; i++)
#pragma unroll
        for (int j = 0; j < 4; j++)
          acc[i][j] = __builtin_amdgcn_mfma_f32_16x16x32_bf16(af[i], bfr[j], acc[i][j], 0, 0, 0);
    }
    __syncthreads();
  }
#pragma unroll
  for (int i = 0; i < 4; i++)
#pragma unroll
    for (int j = 0; j < 4; j++)
#pragma unroll
      for (int r = 0; r < 4; r++){
        const int row = m0 + wr * 64 + i * 16 + (lane >> 4) * 4 + r;
        const int col = n0 + wc * 64 + j * 16 + (lane & 15);
        const float v = acc[i][j][r];
        if constexpr (OUT_BF16) ((unsigned short*)Cp)[(size_t)row * N + col] = f2bf(v);
        else                    ((float*)Cp)[(size_t)row * N + col] = v;
      }
}

// ---------------- RoPE + scatter q,k -> [B,H,N,D] (Q gets 1/8 scale folded) ----------------
__global__ __launch_bounds__(256) void k_rope(const unsigned short* __restrict__ qkv,
                                              const float2* __restrict__ tab,
                                              unsigned short* __restrict__ Qb,
                                              unsigned short* __restrict__ Kb){
  unsigned int idx = blockIdx.x * 256 + threadIdx.x;   // 2*2*16*2048*64 = 8388608
  const int d = idx & 63; idx >>= 6;
  const int n = idx & 2047; idx >>= 11;
  const int h = idx & 15; idx >>= 4;
  const int b = idx & 1;
  const int which = idx >> 1;                           // 0=q, 1=k
  const size_t rowbase = ((size_t)(b * SEQ + n)) * QKV3 + which * DIMC + h * HD;
  const float x0 = bf2f(qkv[rowbase + d]);
  const int dp = (d < 32) ? d + 32 : d - 32;
  const float x1 = bf2f(qkv[rowbase + dp]);
  const float2 cs = tab[n * 32 + (d & 31)];
  const float rot = (d < 32) ? -x1 : x1;
  float y = x0 * cs.x + rot * cs.y;
  if (which == 0) y *= 0.125f;                          // fold 1/sqrt(D) into Q (exact in bf16)
  unsigned short* dst = which ? Kb : Qb;
  dst[(((size_t)(b * NH + h)) * SEQ + n) * HD + d] = f2bf(y);
}

// ---------------- V transpose: qkv v-slice -> Vt[B,H,D,N] ----------------
__global__ __launch_bounds__(256) void k_vt(const unsigned short* __restrict__ qkv,
                                            unsigned short* __restrict__ Vt){
  __shared__ unsigned short t[64 * 72];
  const int tid = threadIdx.x;
  const int nt = blockIdx.x & 31, h = (blockIdx.x >> 5) & 15, b = blockIdx.x >> 9;
  const int n0 = nt * 64;
#pragma unroll
  for (int p = 0; p < 2; p++){
    const int e = p * 2048 + tid * 8;
    const int r = e >> 6, c = e & 63;
    *(bf16x8*)&t[r * 72 + c] =
        *(const bf16x8*)&qkv[((size_t)(b * SEQ + n0 + r)) * QKV3 + 2048 + h * 64 + c];
  }
  __syncthreads();
#pragma unroll
  for (int p = 0; p < 2; p++){
    const int e = p * 2048 + tid * 8;
    const int d = e >> 6, nn = e & 63;
    bf16x8 o;
#pragma unroll
    for (int q = 0; q < 8; q++) o[q] = (short)t[(nn + q) * 72 + d];
    *(bf16x8*)&Vt[(((size_t)(b * NH + h)) * HD + d) * SEQ + n0 + nn] = o;
  }
}

// ---------------- Flash attention: per (b,h) x 128-row Q tile ----------------
// 4 waves x 32 q-rows each; BK=64; S=Q*K^T (K-dim 64), online softmax, P via LDS, PV.
__global__ __launch_bounds__(256) void k_attn(const unsigned short* __restrict__ Q,
                                              const unsigned short* __restrict__ K,
                                              const unsigned short* __restrict__ Vt,
                                              unsigned short* __restrict__ AO){
  __shared__ unsigned short Ks[64 * 72];   // [kv][d]
  __shared__ unsigned short Vs[64 * 72];   // [d][kv]
  __shared__ unsigned short Ps[128 * 72];  // [q][kv]
  const int tid = threadIdx.x, wave = tid >> 6, lane = tid & 63;
  const int qt = blockIdx.x & 15, bh = blockIdx.x >> 4;
  const size_t base = (size_t)bh * (SEQ * HD);
  const int q0 = qt * 128 + wave * 32;

  bf16x8 qf[2][2];
#pragma unroll
  for (int mf = 0; mf < 2; mf++)
#pragma unroll
    for (int ks = 0; ks < 2; ks++)
      qf[mf][ks] = *(const bf16x8*)&Q[base + (size_t)(q0 + mf * 16 + (lane & 15)) * HD
                                      + ks * 32 + (lane >> 4) * 8];
  float mrow[2][4], lrow[2][4];
  f32x4 oacc[2][4];
#pragma unroll
  for (int mf = 0; mf < 2; mf++)
#pragma unroll
    for (int r = 0; r < 4; r++){ mrow[mf][r] = -INFINITY; lrow[mf][r] = 0.f; }
#pragma unroll
  for (int mf = 0; mf < 2; mf++)
#pragma unroll
    for (int df = 0; df < 4; df++) oacc[mf][df] = (f32x4){0.f, 0.f, 0.f, 0.f};

  for (int kv0 = 0; kv0 < SEQ; kv0 += 64){
#pragma unroll
    for (int p = 0; p < 2; p++){
      const int e = p * 2048 + tid * 8;
      const int r = e >> 6, c = e & 63;
      *(bf16x8*)&Ks[r * 72 + c] = *(const bf16x8*)&K[base + (size_t)(kv0 + r) * HD + c];
      *(bf16x8*)&Vs[r * 72 + c] = *(const bf16x8*)&Vt[base + (size_t)r * SEQ + kv0 + c];
    }
    __syncthreads();

    f32x4 s[2][4];
#pragma unroll
    for (int mf = 0; mf < 2; mf++)
#pragma unroll
      for (int nf = 0; nf < 4; nf++) s[mf][nf] = (f32x4){0.f, 0.f, 0.f, 0.f};
#pragma unroll
    for (int ks = 0; ks < 2; ks++){
      const int kk = ks * 32 + (lane >> 4) * 8;
#pragma unroll
      for (int nf = 0; nf < 4; nf++){
        const bf16x8 bfr = *(const bf16x8*)&Ks[(nf * 16 + (lane & 15)) * 72 + kk];
#pragma unroll
        for (int mf = 0; mf < 2; mf++)
          s[mf][nf] = __builtin_amdgcn_mfma_f32_16x16x32_bf16(qf[mf][ks], bfr, s[mf][nf], 0, 0, 0);
      }
    }
    // online softmax (rows: (lane>>4)*4 + r; cols across lane&15 and nf)
#pragma unroll
    for (int mf = 0; mf < 2; mf++){
#pragma unroll
      for (int r = 0; r < 4; r++){
        float mx = fmaxf(fmaxf(s[mf][0][r], s[mf][1][r]), fmaxf(s[mf][2][r], s[mf][3][r]));
        mx = fmaxf(mx, __shfl_xor(mx, 1));
        mx = fmaxf(mx, __shfl_xor(mx, 2));
        mx = fmaxf(mx, __shfl_xor(mx, 4));
        mx = fmaxf(mx, __shfl_xor(mx, 8));
        const float mnew = fmaxf(mrow[mf][r], mx);
        const float alpha = expf(mrow[mf][r] - mnew);
        float rs = 0.f;
#pragma unroll
        for (int nf = 0; nf < 4; nf++){
          const float pv = expf(s[mf][nf][r] - mnew);
          s[mf][nf][r] = pv;
          rs += pv;
        }
        rs += __shfl_xor(rs, 1);
        rs += __shfl_xor(rs, 2);
        rs += __shfl_xor(rs, 4);
        rs += __shfl_xor(rs, 8);
        lrow[mf][r] = lrow[mf][r] * alpha + rs;
        mrow[mf][r] = mnew;
#pragma unroll
        for (int df = 0; df < 4; df++) oacc[mf][df][r] *= alpha;
      }
    }
    // write P (own wave's 32 rows)
#pragma unroll
    for (int mf = 0; mf < 2; mf++)
#pragma unroll
      for (int nf = 0; nf < 4; nf++)
#pragma unroll
        for (int r = 0; r < 4; r++)
          Ps[(wave * 32 + mf * 16 + (lane >> 4) * 4 + r) * 72 + nf * 16 + (lane & 15)] =
              f2bf(s[mf][nf][r]);
    __syncthreads();
    // PV
#pragma unroll
    for (int ks = 0; ks < 2; ks++){
      const int kk = ks * 32 + (lane >> 4) * 8;
      bf16x8 pa[2];
#pragma unroll
      for (int mf = 0; mf < 2; mf++)
        pa[mf] = *(const bf16x8*)&Ps[(wave * 32 + mf * 16 + (lane & 15)) * 72 + kk];
#pragma unroll
      for (int df = 0; df < 4; df++){
        const bf16x8 bfr = *(const bf16x8*)&Vs[(df * 16 + (lane & 15)) * 72 + kk];
#pragma unroll
        for (int mf = 0; mf < 2; mf++)
          oacc[mf][df] = __builtin_amdgcn_mfma_f32_16x16x32_bf16(pa[mf], bfr, oacc[mf][df], 0, 0, 0);
      }
    }
    __syncthreads();
  }
  // epilogue -> AO[b, n, h*64+d] (bf16)
  const int b = bh >> 4, h = bh & 15;
#pragma unroll
  for (int mf = 0; mf < 2; mf++)
#pragma unroll
    for (int df = 0; df < 4; df++)
#pragma unroll
      for (int r = 0; r < 4; r++){
        const int q = q0 + mf * 16 + (lane >> 4) * 4 + r;
        const int d = df * 16 + (lane & 15);
        AO[((size_t)(b * SEQ + q)) * DIMC + h * HD + d] = f2bf(oacc[mf][df][r] / lrow[mf][r]);
      }
}

extern "C" void kernel_launch(void* const* d_in, const int* in_sizes, int n_in,
                              void* d_out, int out_size, void* d_ws, size_t ws_size,
                              hipStream_t stream){
  const float* x     = (const float*)d_in[0];
  const float* Wqkv  = (const float*)d_in[1];
  const float* Wproj = (const float*)d_in[2];
  float* out = (float*)d_out;
  char* ws = (char*)d_ws;

  unsigned short* xb     = (unsigned short*)(ws);               //  8,388,608 B
  unsigned short* wqkvb  = (unsigned short*)(ws +  8388608);    //  6,291,456 B
  unsigned short* wprojb = (unsigned short*)(ws + 14680064);    //  2,097,152 B
  unsigned short* qkvb   = (unsigned short*)(ws + 16777216);    // 25,165,824 B
  float2*         tab    = (float2*)        (ws + 41943040);    //    524,288 B
  unsigned short* Qb     = (unsigned short*)(ws + 42467328);    //  8,388,608 B
  unsigned short* Kb     = (unsigned short*)(ws + 50855936);    //  8,388,608 B
  unsigned short* Vtb    = (unsigned short*)(ws + 59244544);    //  8,388,608 B
  unsigned short* AOb    = (unsigned short*)(ws);               // reuse xb region (xb dead after GEMM1)

  // casts to bf16  (x: 4,194,304 floats = 1,048,576 float4)
  k_cvt<<<4096, 256, 0, stream>>>(x, xb, 1048576);
  k_cvt<<<3072, 256, 0, stream>>>(Wqkv, wqkvb, 786432);
  k_cvt<<<1024, 256, 0, stream>>>(Wproj, wprojb, 262144);
  k_tab<<<256, 256, 0, stream>>>(tab);
  // QKV projection: [4096,1024] x [3072,1024]^T -> bf16 qkv
  k_gemm<1><<<32 * 24, 256, 0, stream>>>(xb, wqkvb, (void*)qkvb, 4096, 3072, 1024);
  // RoPE q,k and V transpose
  k_rope<<<32768, 256, 0, stream>>>(qkvb, tab, Qb, Kb);
  k_vt<<<1024, 256, 0, stream>>>(qkvb, Vtb);
  // flash attention -> AO bf16 [4096,1024]  (AOb aliases xb, which is dead after GEMM1)
  k_attn<<<512, 256, 0, stream>>>(Qb, Kb, Vtb, AOb);
  // output projection: [4096,1024] x [1024,1024]^T -> f32 out
  k_gemm<0><<<32 * 8, 256, 0, stream>>>(AOb, wprojb, (void*)out, 4096, 1024, 1024);
}

// Round 3
// 237.348 us; speedup vs baseline: 1.5439x; 1.5439x over previous
//
#include <hip/hip_runtime.h>
#include <hip/hip_bf16.h>

#define SEQ   2048
#define DIMC  1024
#define NH    16
#define HD    64
#define QKV3  3072
#define NB    2
// 1/sqrt(64) * log2(e), folded into Q so softmax uses exp2 directly
#define SCALE_LOG2E 0.18033688011112042f

typedef __attribute__((ext_vector_type(8)))  short bf16x8;
typedef __attribute__((ext_vector_type(4)))  float f32x4;
typedef __attribute__((ext_vector_type(16))) float f32x16;

__device__ __forceinline__ unsigned short f2bf(float f){
  union { float f; unsigned int u; } v; v.f = f;
  return (unsigned short)((v.u + 0x7fffu + ((v.u >> 16) & 1u)) >> 16);
}
__device__ __forceinline__ float bf2f(unsigned short h){
  union { unsigned int u; float f; } v; v.u = ((unsigned int)h) << 16; return v.f;
}
__device__ __forceinline__ int packbf2(float a, float b){
  __hip_bfloat162 h = __float22bfloat162_rn(make_float2(a, b));  // a -> low16, b -> high16
  int r; __builtin_memcpy(&r, &h, 4); return r;
}
__device__ __forceinline__ void async_lds16(void* lds, const void* g){
  __builtin_amdgcn_global_load_lds(
      (const __attribute__((address_space(1))) void*)g,
      (__attribute__((address_space(3))) void*)lds, 16, 0, 0);
}

// ---------------- f32 -> bf16 convert ----------------
__global__ __launch_bounds__(256) void k_cvt(const float* __restrict__ in,
                                             unsigned short* __restrict__ out, int n4){
  int i = blockIdx.x * 256 + threadIdx.x;
  if (i >= n4) return;
  const float4 v = ((const float4*)in)[i];
  union { unsigned short s[4]; unsigned long long u; } p;
  p.s[0] = f2bf(v.x); p.s[1] = f2bf(v.y); p.s[2] = f2bf(v.z); p.s[3] = f2bf(v.w);
  *(unsigned long long*)(out + (size_t)i * 4) = p.u;
}

// ---------------- RoPE cos/sin table ----------------
__global__ __launch_bounds__(256) void k_tab(float2* __restrict__ tab){
  int idx = blockIdx.x * 256 + threadIdx.x;          // 2048*32
  int n = idx >> 5, j = idx & 31;
  float inv = 1.0f / powf(10000.0f, (float)(2 * j) * (1.0f / 64.0f));
  float f = (float)n * inv;
  tab[idx] = make_float2(cosf(f), sinf(f));
}

// ---------------- GEMM: C[M,N] = A[M,K] * B[N,K]^T (m97 structure) ----------------
template<int OUT_BF16>
__global__ __launch_bounds__(256) void k_gemm(const unsigned short* __restrict__ A,
                                              const unsigned short* __restrict__ Bm,
                                              void* __restrict__ Cp, int M, int N, int K){
  __shared__ unsigned short As[128 * 64];
  __shared__ unsigned short Bs[128 * 64];
  const int tid = threadIdx.x, wave = tid >> 6, lane = tid & 63;
  const int nbn = N >> 7;
  const int bm = blockIdx.x / nbn, bn = blockIdx.x % nbn;
  const int m0 = bm << 7, n0 = bn << 7;
  const int wr = wave >> 1, wc = wave & 1;

  f32x4 acc[4][4];
#pragma unroll
  for (int i = 0; i < 4; i++)
#pragma unroll
    for (int j = 0; j < 4; j++) acc[i][j] = (f32x4){0.f, 0.f, 0.f, 0.f};

  for (int k0 = 0; k0 < K; k0 += 64){
#pragma unroll
    for (int c = 0; c < 4; c++){
      const int e = c * 2048 + tid * 8;
      const int row = e >> 6, col = e & 63;
      async_lds16(As + c * 2048 + wave * 512, A + (size_t)(m0 + row) * K + k0 + col);
      async_lds16(Bs + c * 2048 + wave * 512, Bm + (size_t)(n0 + row) * K + k0 + col);
    }
    __syncthreads();
#pragma unroll
    for (int ks = 0; ks < 2; ks++){
      const int kk = ks * 32 + (lane >> 4) * 8;
      bf16x8 af[4], bfr[4];
#pragma unroll
      for (int i = 0; i < 4; i++){
        af[i]  = *(const bf16x8*)&As[(wr * 64 + i * 16 + (lane & 15)) * 64 + kk];
        bfr[i] = *(const bf16x8*)&Bs[(wc * 64 + i * 16 + (lane & 15)) * 64 + kk];
      }
#pragma unroll
      for (int i = 0; i < 4; i++)
#pragma unroll
        for (int j = 0; j < 4; j++)
          acc[i][j] = __builtin_amdgcn_mfma_f32_16x16x32_bf16(af[i], bfr[j], acc[i][j], 0, 0, 0);
    }
    __syncthreads();
  }
#pragma unroll
  for (int i = 0; i < 4; i++)
#pragma unroll
    for (int j = 0; j < 4; j++)
#pragma unroll
      for (int r = 0; r < 4; r++){
        const int row = m0 + wr * 64 + i * 16 + (lane >> 4) * 4 + r;
        const int col = n0 + wc * 64 + j * 16 + (lane & 15);
        const float v = acc[i][j][r];
        if constexpr (OUT_BF16) ((unsigned short*)Cp)[(size_t)row * N + col] = f2bf(v);
        else                    ((float*)Cp)[(size_t)row * N + col] = v;
      }
}

// ---------------- RoPE (vectorized): Q (log2e-scaled, linear) / K (XOR-swizzled cols) ----------------
// Kswz[(bh)*SEQ*HD + n*64 + (d ^ ((n&7)<<3))] = rope(K)[n][d]
__global__ __launch_bounds__(256) void k_rope(const unsigned short* __restrict__ qkv,
                                              const float2* __restrict__ tab,
                                              unsigned short* __restrict__ Qb,
                                              unsigned short* __restrict__ Kswz){
  unsigned int idx = blockIdx.x * 256 + threadIdx.x;   // 2*2*16*2048*4 = 524288
  const int j = idx & 3; idx >>= 2;
  const int n = idx & 2047; idx >>= 11;
  const int h = idx & 15; idx >>= 4;
  const int b = idx & 1;
  const int which = idx >> 1;                           // 0=q, 1=k
  const size_t rowbase = ((size_t)(b * SEQ + n)) * QKV3 + which * DIMC + h * HD;
  const bf16x8 lo = *(const bf16x8*)&qkv[rowbase + j * 8];
  const bf16x8 hi = *(const bf16x8*)&qkv[rowbase + 32 + j * 8];
  union { unsigned short s[8]; bf16x8 v; } olo, ohi;
#pragma unroll
  for (int t = 0; t < 8; t++){
    const float2 cs = tab[n * 32 + j * 8 + t];
    const float xl = bf2f((unsigned short)lo[t]), xh = bf2f((unsigned short)hi[t]);
    float yl = xl * cs.x - xh * cs.y;       // d < 32: x*cos - x[d+32]*sin
    float yh = xh * cs.x + xl * cs.y;       // d >= 32: x*cos + x[d-32]*sin
    if (which == 0){ yl *= SCALE_LOG2E; yh *= SCALE_LOG2E; }
    olo.s[t] = f2bf(yl); ohi.s[t] = f2bf(yh);
  }
  const size_t orow = (((size_t)(b * NH + h)) * SEQ + n) * HD;
  if (which == 0){
    *(bf16x8*)&Qb[orow + j * 8]      = olo.v;
    *(bf16x8*)&Qb[orow + 32 + j * 8] = ohi.v;
  } else {
    const int s = (n & 7) << 3;
    *(bf16x8*)&Kswz[orow + ((j * 8) ^ s)]      = olo.v;
    *(bf16x8*)&Kswz[orow + ((32 + j * 8) ^ s)] = ohi.v;
  }
}

// ---------------- V transpose: qkv v-slice -> Vtswz[B,H,D,N], XOR-swizzled within 64-col tiles ----
// Vtswz[d][n0 + c] = V[n0 + (c ^ ((d&7)<<3))][d]
__global__ __launch_bounds__(256) void k_vt(const unsigned short* __restrict__ qkv,
                                            unsigned short* __restrict__ Vt){
  __shared__ unsigned short t[64 * 72];
  const int tid = threadIdx.x;
  const int nt = blockIdx.x & 31, h = (blockIdx.x >> 5) & 15, b = blockIdx.x >> 9;
  const int n0 = nt * 64;
#pragma unroll
  for (int p = 0; p < 2; p++){
    const int e = p * 2048 + tid * 8;
    const int r = e >> 6, c = e & 63;
    *(bf16x8*)&t[r * 72 + c] =
        *(const bf16x8*)&qkv[((size_t)(b * SEQ + n0 + r)) * QKV3 + 2048 + h * 64 + c];
  }
  __syncthreads();
#pragma unroll
  for (int p = 0; p < 2; p++){
    const int e = p * 2048 + tid * 8;
    const int d = e >> 6, nn = e & 63;
    const int sw = (d & 7) << 3;
    union { unsigned short s[8]; bf16x8 v; } o;
#pragma unroll
    for (int q = 0; q < 8; q++) o.s[q] = t[((nn ^ sw) + q) * 72 + d];
    *(bf16x8*)&Vt[(((size_t)(b * NH + h)) * HD + d) * SEQ + n0 + nn] = o.v;
  }
}

// ---------------- Flash attention (m214-style): 4 waves x 32 q-rows, swapped 32x32 MFMA ----------
// QK^T = mfma(K,Q): lane holds S[kv-slice][q=lane&31] -> in-register softmax (1 shfl).
// PV = mfma(V^T,P): lane holds O^T[d-slice][q=lane&31] -> lane-local l/alpha.
__global__ __launch_bounds__(256) void k_attn(const unsigned short* __restrict__ Q,
                                              const unsigned short* __restrict__ Kg,
                                              const unsigned short* __restrict__ Vg,
                                              unsigned short* __restrict__ AO){
  __shared__ unsigned short Ks[64 * 64];   // [kv][d^swz]
  __shared__ unsigned short Vs[64 * 64];   // [d][kv^swz]
  const int tid = threadIdx.x, wave = tid >> 6, lane = tid & 63;
  const int bh = blockIdx.x & 31, qt = blockIdx.x >> 5;   // bh in low bits: heads pin to XCDs
  const size_t base = (size_t)bh * (SEQ * HD);
  const int q32 = lane & 31, hi = lane >> 5, hi8 = hi << 3;
  const int sw = (q32 & 7) << 3;
  const int q0w = qt * 128 + wave * 32;

  // Q fragments: qf[kc][e] = Q[q0w+q32][kc*16 + hi*8 + e]
  bf16x8 qf[4];
#pragma unroll
  for (int kc = 0; kc < 4; kc++)
    qf[kc] = *(const bf16x8*)&Q[base + (size_t)(q0w + q32) * HD + kc * 16 + hi8];

  f32x16 oacc[2];
#pragma unroll
  for (int md = 0; md < 2; md++)
#pragma unroll
    for (int r = 0; r < 16; r++) oacc[md][r] = 0.f;
  float mrow = -INFINITY, lrow = 0.f;

  // staging geometry: chunk c covers rows [c*8, c*8+8), lane -> row c*8+(lane>>3), col (lane&7)*8
  const int srow = lane >> 3, scol = (lane & 7) * 8;

  for (int kv0 = 0; kv0 < SEQ; kv0 += 64){
#pragma unroll
    for (int i = 0; i < 2; i++){
      const int c = wave * 2 + i;
      const int row = c * 8 + srow;
      async_lds16(&Ks[c * 512], &Kg[base + (size_t)(kv0 + row) * HD + scol]);
      async_lds16(&Vs[c * 512], &Vg[base + (size_t)row * SEQ + kv0 + scol]);
    }
    __syncthreads();

    // ---- QK^T: s0 (kv 0..31), s1 (kv 32..63); reg r -> kv = kappa*32 + (r&3)+8*(r>>2)+4*hi
    f32x16 s0, s1;
#pragma unroll
    for (int r = 0; r < 16; r++){ s0[r] = 0.f; s1[r] = 0.f; }
#pragma unroll
    for (int kc = 0; kc < 4; kc++){
      const int col = (kc * 16 + hi8) ^ sw;
      const bf16x8 k0 = *(const bf16x8*)&Ks[q32 * 64 + col];
      const bf16x8 k1 = *(const bf16x8*)&Ks[(32 + q32) * 64 + col];
      s0 = __builtin_amdgcn_mfma_f32_32x32x16_bf16(k0, qf[kc], s0, 0, 0, 0);
      s1 = __builtin_amdgcn_mfma_f32_32x32x16_bf16(k1, qf[kc], s1, 0, 0, 0);
    }

    // ---- online softmax (log2-domain), fully per-lane + one cross-half shfl
    float mx = fmaxf(s0[0], s0[1]);
#pragma unroll
    for (int r = 2; r < 16; r++) mx = fmaxf(mx, s0[r]);
#pragma unroll
    for (int r = 0; r < 16; r++) mx = fmaxf(mx, s1[r]);
    mx = fmaxf(mx, __shfl_xor(mx, 32));
    const float mnew = fmaxf(mrow, mx);
    const float alpha = __builtin_amdgcn_exp2f(mrow - mnew);
#pragma unroll
    for (int r = 0; r < 16; r++){
      s0[r] = __builtin_amdgcn_exp2f(s0[r] - mnew);
      s1[r] = __builtin_amdgcn_exp2f(s1[r] - mnew);
    }
    float rs = 0.f;
#pragma unroll
    for (int r = 0; r < 16; r++) rs += s0[r] + s1[r];
    rs += __shfl_xor(rs, 32);
    lrow = lrow * alpha + rs;
    mrow = mnew;
#pragma unroll
    for (int md = 0; md < 2; md++)
#pragma unroll
      for (int r = 0; r < 16; r++) oacc[md][r] *= alpha;

    // ---- P -> bf16 frags (register-only exchange) + PV
    // block g holds kv = 8g + 4*hi + {0..3}; frag[g2] needs kv = g2*16 + hi*8 + e
#pragma unroll
    for (int g2 = 0; g2 < 4; g2++){
      float pj[8];
#pragma unroll
      for (int t = 0; t < 8; t++) pj[t] = (g2 < 2) ? s0[(g2 & 1) * 8 + t] : s1[(g2 & 1) * 8 + t];
      const int X0 = packbf2(pj[0], pj[1]), X1 = packbf2(pj[2], pj[3]);
      const int Y0 = packbf2(pj[4], pj[5]), Y1 = packbf2(pj[6], pj[7]);
      const int pX0 = __shfl_xor(X0, 32), pX1 = __shfl_xor(X1, 32);
      const int pY0 = __shfl_xor(Y0, 32), pY1 = __shfl_xor(Y1, 32);
      union { int w[4]; bf16x8 v; } pb;
      pb.w[0] = hi ? pY0 : X0;
      pb.w[1] = hi ? pY1 : X1;
      pb.w[2] = hi ? Y0 : pX0;
      pb.w[3] = hi ? Y1 : pX1;
#pragma unroll
      for (int md = 0; md < 2; md++){
        const bf16x8 av = *(const bf16x8*)&Vs[(md * 32 + q32) * 64 + ((g2 * 16 + hi8) ^ sw)];
        oacc[md] = __builtin_amdgcn_mfma_f32_32x32x16_bf16(av, pb.v, oacc[md], 0, 0, 0);
      }
    }
    __syncthreads();
  }

  // ---- epilogue: O[q][d] = oacc^T / lrow ; d = md*32 + 8a + 4*hi + b
  const float rl = 1.0f / lrow;
  const int b = bh >> 4, h = bh & 15;
  const size_t obase = ((size_t)(b * SEQ + q0w + q32)) * DIMC + h * HD;
#pragma unroll
  for (int md = 0; md < 2; md++)
#pragma unroll
    for (int a = 0; a < 4; a++){
      const int d0 = md * 32 + a * 8 + hi * 4;
      int2 wv;
      wv.x = packbf2(oacc[md][a * 4 + 0] * rl, oacc[md][a * 4 + 1] * rl);
      wv.y = packbf2(oacc[md][a * 4 + 2] * rl, oacc[md][a * 4 + 3] * rl);
      *(int2*)&AO[obase + d0] = wv;
    }
}

extern "C" void kernel_launch(void* const* d_in, const int* in_sizes, int n_in,
                              void* d_out, int out_size, void* d_ws, size_t ws_size,
                              hipStream_t stream){
  const float* x     = (const float*)d_in[0];
  const float* Wqkv  = (const float*)d_in[1];
  const float* Wproj = (const float*)d_in[2];
  float* out = (float*)d_out;
  char* ws = (char*)d_ws;

  unsigned short* xb     = (unsigned short*)(ws);               //  8,388,608 B
  unsigned short* wqkvb  = (unsigned short*)(ws +  8388608);    //  6,291,456 B
  unsigned short* wprojb = (unsigned short*)(ws + 14680064);    //  2,097,152 B
  unsigned short* qkvb   = (unsigned short*)(ws + 16777216);    // 25,165,824 B
  float2*         tab    = (float2*)        (ws + 41943040);    //    524,288 B
  unsigned short* Qb     = (unsigned short*)(ws + 42467328);    //  8,388,608 B
  unsigned short* Kb     = (unsigned short*)(ws + 50855936);    //  8,388,608 B
  unsigned short* Vtb    = (unsigned short*)(ws + 59244544);    //  8,388,608 B
  unsigned short* AOb    = (unsigned short*)(ws);               // reuse xb (dead after GEMM1)

  k_cvt<<<4096, 256, 0, stream>>>(x, xb, 1048576);
  k_cvt<<<3072, 256, 0, stream>>>(Wqkv, wqkvb, 786432);
  k_cvt<<<1024, 256, 0, stream>>>(Wproj, wprojb, 262144);
  k_tab<<<256, 256, 0, stream>>>(tab);
  // QKV projection
  k_gemm<1><<<32 * 24, 256, 0, stream>>>(xb, wqkvb, (void*)qkvb, 4096, 3072, 1024);
  // RoPE q (scaled) / k (swizzled), V transpose (swizzled)
  k_rope<<<2048, 256, 0, stream>>>(qkvb, tab, Qb, Kb);
  k_vt<<<1024, 256, 0, stream>>>(qkvb, Vtb);
  // flash attention
  k_attn<<<512, 256, 0, stream>>>(Qb, Kb, Vtb, AOb);
  // output projection
  k_gemm<0><<<32 * 8, 256, 0, stream>>>(AOb, wprojb, (void*)out, 4096, 1024, 1024);
}